// Round 4
// baseline (695.369 us; speedup 1.0000x reference)
//
#include <hip/hip_runtime.h>
#include <math.h>

#define EPSF 1e-8f

constexpr int Bn = 16, Cc = 256, HW = 1024, Ee = 512, Vv = 8192;
constexpr int Mm = Bn * HW; // 16384 pixels

// d_out float offsets: z | z_q | decoder_input | tokens(float)
constexpr long O_Z   = 0;
constexpr long O_ZQ  = 8388608;
constexpr long O_DEC = 16777216;
constexpr long O_TOK = 25165824;

typedef __attribute__((ext_vector_type(8))) short bf16x8;
typedef __attribute__((ext_vector_type(4))) short bf16x4;
typedef __attribute__((ext_vector_type(4))) float f32x4;

__device__ __forceinline__ unsigned short f2bf(float x) {
    unsigned int u = __float_as_uint(x);
    unsigned int r = (u + 0x7FFFu + ((u >> 16) & 1u)) >> 16;   // RNE
    return (unsigned short)r;
}
__device__ __forceinline__ float bf2f(unsigned short h) {
    return __uint_as_float(((unsigned int)h) << 16);
}

// ---------------- small prep kernels ----------------

__global__ void k_wT(const float* __restrict__ w, float* __restrict__ wT) {
    int gid = blockIdx.x * 256 + threadIdx.x;      // 0..131071
    int c = gid >> 9, e = gid & 511;
    wT[gid] = w[e * Cc + c];                        // wT[c][e]
}

__global__ void k_en(const float* __restrict__ emb, float* __restrict__ en_inv,
                     float* __restrict__ en_norm) {
    int v = blockIdx.x * 4 + (threadIdx.x >> 6);    // one wave per row
    int lane = threadIdx.x & 63;
    const float* row = emb + (long)v * Ee;
    float s = 0.f;
#pragma unroll
    for (int j = 0; j < 8; ++j) { float xv = row[lane + 64 * j]; s += xv * xv; }
#pragma unroll
    for (int off = 32; off; off >>= 1) s += __shfl_xor(s, off);
    if (lane == 0) {
        float n = sqrtf(s);
        en_norm[v] = EPSF + n;
        en_inv[v]  = 1.0f / (EPSF + n);
    }
}

// ---------------- GEMM1: z[b][e][hw] = sum_c x[b][c][hw]*w[e][c] + b[e] ----------------

__global__ __launch_bounds__(256) void k_gemm1(const float* __restrict__ x,
                                               const float* __restrict__ wT,
                                               const float* __restrict__ bias,
                                               float* __restrict__ z) {
    __shared__ float As[32][64];
    __shared__ float Bs[32][64];
    int m0 = blockIdx.x * 64;                 // pixel tile
    int b = m0 >> 10, hw0 = m0 & 1023;
    int e0 = blockIdx.y * 64;
    int t = threadIdx.x;
    int mi = t >> 4, ni = t & 15;
    float acc[4][4] = {};
    for (int c0 = 0; c0 < Cc; c0 += 32) {
#pragma unroll
        for (int q = 0; q < 2; ++q) {
            int f = t + 256 * q;
            int kk = f >> 4, m4 = (f & 15) * 4;
            *(float4*)&As[kk][m4] = *(const float4*)(x + ((long)(b * Cc + c0 + kk)) * HW + hw0 + m4);
            *(float4*)&Bs[kk][m4] = *(const float4*)(wT + (long)(c0 + kk) * Ee + e0 + m4);
        }
        __syncthreads();
#pragma unroll
        for (int kk = 0; kk < 32; ++kk) {
            float4 a = *(float4*)&As[kk][mi * 4];
            float4 bv = *(float4*)&Bs[kk][ni * 4];
            float av[4] = {a.x, a.y, a.z, a.w};
            float bb[4] = {bv.x, bv.y, bv.z, bv.w};
#pragma unroll
            for (int r = 0; r < 4; ++r)
#pragma unroll
                for (int c = 0; c < 4; ++c) acc[r][c] = fmaf(av[r], bb[c], acc[r][c]);
        }
        __syncthreads();
    }
#pragma unroll
    for (int c = 0; c < 4; ++c) {
        int e = e0 + ni * 4 + c;
        float be = bias[e];
        float4 o = make_float4(acc[0][c] + be, acc[1][c] + be, acc[2][c] + be, acc[3][c] + be);
        *(float4*)(z + ((long)(b * Ee + e)) * HW + hw0 + mi * 4) = o;
    }
}

// per-pixel 1/(EPS+||z||) over E
__global__ void k_znorm(const float* __restrict__ z, float* __restrict__ inv_zn) {
    int p = blockIdx.x * 256 + threadIdx.x;
    int b = p >> 10, hw = p & 1023;
    const float* base = z + (long)b * Ee * HW + hw;
    float s = 0.f;
    for (int e = 0; e < Ee; ++e) { float xv = base[(long)e * HW]; s += xv * xv; }
    inv_zn[p] = 1.0f / (EPSF + sqrtf(s));
}

// ---------------- A split: zn -> A_hi/A_lo bf16 [16384][512] (pixel-major) ----------------

__global__ void k_Asplit(const float* __restrict__ z, const float* __restrict__ inv_zn,
                         unsigned short* __restrict__ Ahi, unsigned short* __restrict__ Alo) {
    __shared__ float tile[64][65];
    int p0 = (blockIdx.x >> 3) * 64;   // 256 p-tiles
    int e0 = (blockIdx.x & 7) * 64;    // 8 e-tiles
    int b = p0 >> 10, hw0 = p0 & 1023;
    int t = threadIdx.x;
#pragma unroll
    for (int q = 0; q < 4; ++q) {
        int f = t + 256 * q;
        int e_l = f >> 4, p4 = (f & 15) * 4;
        float4 d = *(const float4*)(z + ((long)(b * Ee + e0 + e_l)) * HW + hw0 + p4);
        tile[e_l][p4 + 0] = d.x; tile[e_l][p4 + 1] = d.y;
        tile[e_l][p4 + 2] = d.z; tile[e_l][p4 + 3] = d.w;
    }
    __syncthreads();
#pragma unroll
    for (int q = 0; q < 4; ++q) {
        int f = t + 256 * q;
        int p_l = f >> 4, e4 = (f & 15) * 4;
        float inv = inv_zn[p0 + p_l];
        bf16x4 h, lo;
#pragma unroll
        for (int j = 0; j < 4; ++j) {
            float xv = tile[e4 + j][p_l] * inv;
            unsigned short hh = f2bf(xv);
            h[j]  = (short)hh;
            lo[j] = (short)f2bf(xv - bf2f(hh));
        }
        long off = (long)(p0 + p_l) * Ee + e0 + e4;
        *(bf16x4*)(Ahi + off) = h;
        *(bf16x4*)(Alo + off) = lo;
    }
}

// ---------------- B split: emb*en_inv -> B_hi/B_lo bf16 [8192][512] (v-major) ----------------

__global__ void k_Bsplit(const float* __restrict__ emb, const float* __restrict__ en_inv,
                         unsigned short* __restrict__ Bhi, unsigned short* __restrict__ Blo) {
    int gid = blockIdx.x * 256 + threadIdx.x;   // 0..1048575
    int v = gid >> 7, c4 = (gid & 127) * 4;
    float inv = en_inv[v];
    float4 d = *(const float4*)(emb + (long)v * Ee + c4);
    float xs[4] = {d.x * inv, d.y * inv, d.z * inv, d.w * inv};
    bf16x4 h, lo;
#pragma unroll
    for (int j = 0; j < 4; ++j) {
        unsigned short hh = f2bf(xs[j]);
        h[j]  = (short)hh;
        lo[j] = (short)f2bf(xs[j] - bf2f(hh));
    }
    long off = (long)v * Ee + c4;
    *(bf16x4*)(Bhi + off) = h;
    *(bf16x4*)(Blo + off) = lo;
}

// ---------------- 8-phase 256x256 MFMA sims GEMM + per-block argmax ----------------
// 2048 blocks (64 m x 32 v), 512 thr = 8 waves (wr 0..1, wc 0..3).
// K = 24 tiles of 64 (3 segments x 8). 12 iterations x 8 phases (2 tiles/iter).
// Wave output = 4 disjoint 64x32 patches: phase quadrant (mh,nh) -> rows
// mh*128+wr*64..+63, cols nh*128+wc*32..+31  => each phase reads exactly one
// A-half + one B-half -> half-tile-granular staging into freed LDS regions.
// Staging: global_load_lds x16B, linear LDS dest, pre-swizzled global source
// (slot s' = s ^ (r&7)); readers apply the same XOR. Counted vmcnt(4) ONLY
// before the end-barriers of phases 4 and 8 (wait-then-barrier covers all
// waves' DMAs). Raw s_barrier x2/phase; setprio around MFMA clusters.

template<int MH, int NH>
__device__ __forceinline__ void mfma_phase(f32x4 (&acc)[2][2][4][2],
                                           bf16x8 (&af)[4][2], bf16x8 (&bfr)[2][2]) {
#pragma unroll
    for (int kk = 0; kk < 2; ++kk)
#pragma unroll
        for (int mf = 0; mf < 4; ++mf)
#pragma unroll
            for (int nf = 0; nf < 2; ++nf)
                acc[MH][NH][mf][nf] = __builtin_amdgcn_mfma_f32_16x16x32_bf16(
                    af[mf][kk], bfr[nf][kk], acc[MH][NH][mf][nf], 0, 0, 0);
}

__global__ __launch_bounds__(512, 2) void k_sims(const unsigned short* __restrict__ Ahi,
                                                 const unsigned short* __restrict__ Alo,
                                                 const unsigned short* __restrict__ Bhi,
                                                 const unsigned short* __restrict__ Blo,
                                                 float* __restrict__ part_v,
                                                 int* __restrict__ part_i) {
    __shared__ short As[2][2][8192];   // [buf][half][r*64 + slot*8 + e]  16KB each
    __shared__ short Bs[2][2][8192];

    const int t = threadIdx.x;
    const int wid = t >> 6, l = t & 63;
    const int wr = wid >> 2, wc = wid & 3;
    const int l15 = l & 15, lg = l >> 4;

    int wg = blockIdx.x;
    int newid = (wg & 7) * 256 + (wg >> 3);      // XCD-chunked (2048 % 8 == 0)
    int bx = newid & 63, by = newid >> 6;
    const long m0 = (long)bx * 256, n0 = (long)by * 256;

    // ---- staging: one half-tile (128 rows x 64 k) = 2 x global_load_lds/thread
    auto stage = [&](const unsigned short* gbase, short* region, long row0, int k0) {
#pragma unroll
        for (int j = 0; j < 2; ++j) {
            int i = j * 512 + t;               // 16B-slot index 0..1023
            int r = i >> 3, s = i & 7;
            int sp = s ^ (r & 7);              // pre-swizzled global source
            const unsigned short* gp = gbase + (row0 + r) * Ee + k0 + sp * 8;
            short* lp = region + (long)(j * 512 + (t & ~63)) * 8;  // wave-uniform
            __builtin_amdgcn_global_load_lds(
                (const __attribute__((address_space(1))) unsigned int*)gp,
                (__attribute__((address_space(3))) unsigned int*)lp, 16, 0, 0);
        }
    };
    auto stageA = [&](int T, int half) {
        if (T >= 24) return;
        int k0 = (T & 7) * 64;
        stage((T >> 3) == 2 ? Alo : Ahi, &As[T & 1][half][0], m0 + half * 128, k0);
    };
    auto stageB = [&](int T, int half) {
        if (T >= 24) return;
        int k0 = (T & 7) * 64;
        stage((T >> 3) == 1 ? Blo : Bhi, &Bs[T & 1][half][0], n0 + half * 128, k0);
    };

    bf16x8 af[4][2], bfr[2][2];
    auto readAh = [&](int buf, int half) {
#pragma unroll
        for (int mf = 0; mf < 4; ++mf)
#pragma unroll
            for (int kk = 0; kk < 2; ++kk) {
                int r = wr * 64 + mf * 16 + l15;
                int g = kk * 4 + lg;
                af[mf][kk] = *(const bf16x8*)&As[buf][half][r * 64 + ((g ^ (r & 7)) << 3)];
            }
    };
    auto readBh = [&](int buf, int half) {
#pragma unroll
        for (int nf = 0; nf < 2; ++nf)
#pragma unroll
            for (int kk = 0; kk < 2; ++kk) {
                int r = wc * 32 + nf * 16 + l15;
                int g = kk * 4 + lg;
                bfr[nf][kk] = *(const bf16x8*)&Bs[buf][half][r * 64 + ((g ^ (r & 7)) << 3)];
            }
    };

    f32x4 acc[2][2][4][2];
#pragma unroll
    for (int a = 0; a < 2; ++a)
#pragma unroll
        for (int b = 0; b < 2; ++b)
#pragma unroll
            for (int c = 0; c < 4; ++c)
#pragma unroll
                for (int d = 0; d < 2; ++d) acc[a][b][c][d] = (f32x4){0.f, 0.f, 0.f, 0.f};

    // ---- prologue: tiles 0 and 1 fully staged
    stageA(0, 0); stageA(0, 1); stageB(0, 0); stageB(0, 1);
    stageA(1, 0); stageA(1, 1); stageB(1, 0); stageB(1, 1);
    asm volatile("s_waitcnt vmcnt(0)" ::: "memory");
    __builtin_amdgcn_s_barrier();

#define BAR() __builtin_amdgcn_s_barrier()
#define PRIO1() __builtin_amdgcn_s_setprio(1)
#define PRIO0() __builtin_amdgcn_s_setprio(0)

    for (int it = 0; it < 12; ++it) {
        int t0 = 2 * it, t1 = 2 * it + 1;
        // P1: tile t0 (buf0) quad (0,0); stage A1(t1)->buf1
        readAh(0, 0); readBh(0, 0); stageA(t1, 1);
        BAR(); PRIO1(); mfma_phase<0, 0>(acc, af, bfr); PRIO0(); BAR();
        // P2: (0,1) reuse A0; stage B0(t1)
        readBh(0, 1); stageB(t1, 0);
        BAR(); PRIO1(); mfma_phase<0, 1>(acc, af, bfr); PRIO0(); BAR();
        // P3: (1,1) reuse B1; stage A0(t0+2)  [A0(t0) free since end P2]
        readAh(0, 1); stageA(t0 + 2, 0);
        BAR(); PRIO1(); mfma_phase<1, 1>(acc, af, bfr); PRIO0(); BAR();
        // P4: (1,0) reuse A1; stage B1(t0+2); counted wait covers <=P2 stagings
        readBh(0, 0); stageB(t0 + 2, 1);
        BAR(); PRIO1(); mfma_phase<1, 0>(acc, af, bfr); PRIO0();
        asm volatile("s_waitcnt vmcnt(4)" ::: "memory");
        BAR();
        // P5: tile t1 (buf1) quad (0,0); stage A1(t0+2)
        readAh(1, 0); readBh(1, 0); stageA(t0 + 2, 1);
        BAR(); PRIO1(); mfma_phase<0, 0>(acc, af, bfr); PRIO0(); BAR();
        // P6: (0,1); stage B0(t0+2)
        readBh(1, 1); stageB(t0 + 2, 0);
        BAR(); PRIO1(); mfma_phase<0, 1>(acc, af, bfr); PRIO0(); BAR();
        // P7: (1,1); stage A0(t0+3)
        readAh(1, 1); stageA(t0 + 3, 0);
        BAR(); PRIO1(); mfma_phase<1, 1>(acc, af, bfr); PRIO0(); BAR();
        // P8: (1,0); stage B1(t0+3); counted wait covers <=P6 stagings
        readBh(1, 0); stageB(t0 + 3, 1);
        BAR(); PRIO1(); mfma_phase<1, 0>(acc, af, bfr); PRIO0();
        asm volatile("s_waitcnt vmcnt(4)" ::: "memory");
        BAR();
    }

    asm volatile("s_waitcnt vmcnt(0)" ::: "memory");
    __builtin_amdgcn_s_barrier();

    // ---- per-block argmax epilogue (C/D: col = l&15, row = (l>>4)*4 + reg) ----
    float* red_v = (float*)&As[0][0][0];   // 4KB, overlaid (all LDS reads done)
    int*   red_i = (int*)&Bs[0][0][0];
#pragma unroll
    for (int mh = 0; mh < 2; ++mh)
#pragma unroll
        for (int mf = 0; mf < 4; ++mf)
#pragma unroll
            for (int rg = 0; rg < 4; ++rg) {
                float best = -3e38f; int bi = 0;
#pragma unroll
                for (int nh = 0; nh < 2; ++nh)
#pragma unroll
                    for (int nf = 0; nf < 2; ++nf) {
                        float val = acc[mh][nh][mf][nf][rg];
                        int idx = (int)n0 + nh * 128 + wc * 32 + nf * 16 + l15;
                        if (val > best) { best = val; bi = idx; }
                    }
#pragma unroll
                for (int off = 1; off < 16; off <<= 1) {
                    float ov = __shfl_xor(best, off);
                    int oi = __shfl_xor(bi, off);
                    if (ov > best || (ov == best && oi < bi)) { best = ov; bi = oi; }
                }
                if (l15 == 0) {
                    int m_l = mh * 128 + wr * 64 + mf * 16 + lg * 4 + rg;
                    red_v[wc * 256 + m_l] = best;
                    red_i[wc * 256 + m_l] = bi;
                }
            }
    __syncthreads();
    if (t < 256) {
        float best = red_v[t]; int bi = red_i[t];
#pragma unroll
        for (int w2 = 1; w2 < 4; ++w2) {
            float v2 = red_v[w2 * 256 + t]; int i2 = red_i[w2 * 256 + t];
            if (v2 > best || (v2 == best && i2 < bi)) { best = v2; bi = i2; }
        }
        long m = m0 + t;
        part_v[m * 32 + by] = best;
        part_i[m * 32 + by] = bi;
    }
}

// ---------------- merge 32 partials per pixel ----------------

__global__ void k_reduce(const float* __restrict__ part_v, const int* __restrict__ part_i,
                         int* __restrict__ tok_i, float* __restrict__ tok_f) {
    int p = blockIdx.x * 8 + (threadIdx.x >> 5);
    int lane = threadIdx.x & 31;
    float v = part_v[(long)p * 32 + lane];
    int i = part_i[(long)p * 32 + lane];
#pragma unroll
    for (int off = 1; off < 32; off <<= 1) {
        float ov = __shfl_xor(v, off);
        int oi = __shfl_xor(i, off);
        if (ov > v || (ov == v && oi < i)) { v = ov; i = oi; }
    }
    if (lane == 0) { tok_i[p] = i; tok_f[p] = (float)i; }
}

// ---------------- finalize: z_q gather + straight-through blend ----------------

__global__ void k_final(const float* __restrict__ z, const float* __restrict__ emb,
                        const int* __restrict__ tok, const float* __restrict__ inv_zn,
                        const float* __restrict__ en_inv, const float* __restrict__ en_norm,
                        float* __restrict__ zq, float* __restrict__ dec) {
    long gid = (long)blockIdx.x * 256 + threadIdx.x;   // 0..8388607
    int hw = (int)(gid & 1023);
    int b  = (int)(gid >> 19);
    int p  = (b << 10) | hw;
    int e  = (int)((gid >> 10) & 511);
    int tk = tok[p];
    float zqv = emb[(long)tk * Ee + e];
    float nq  = en_norm[tk];
    float nzq = zqv * en_inv[tk];
    float zv  = z[gid];
    float nz  = zv * inv_zn[p];
    zq[gid]  = zqv;
    dec[gid] = (nz + (nzq - nz)) * nq;
}

// ---------------- launch ----------------

extern "C" void kernel_launch(void* const* d_in, const int* in_sizes, int n_in,
                              void* d_out, int out_size, void* d_ws, size_t ws_size,
                              hipStream_t stream) {
    const float* x     = (const float*)d_in[0];
    const float* w_pre = (const float*)d_in[1];
    const float* b_pre = (const float*)d_in[2];
    const float* emb   = (const float*)d_in[3];

    float* out  = (float*)d_out;
    float* z    = out + O_Z;
    float* zq   = out + O_ZQ;
    float* dec  = out + O_DEC;
    float* tokf = out + O_TOK;

    // zq region (32MB): A_hi | A_lo   (dead until k_final)
    unsigned short* Ahi = (unsigned short*)zq;
    unsigned short* Alo = Ahi + (long)Mm * Ee;
    // dec region (32MB): B_hi | B_lo | part_v | part_i
    unsigned short* Bhi = (unsigned short*)dec;
    unsigned short* Blo = Bhi + (long)Vv * Ee;
    float* part_v = dec + 4 * 1024 * 1024;           // +16MB (2MB used)
    int*   part_i = (int*)(dec + 5 * 1024 * 1024);   // +20MB (2MB used)

    float* ws      = (float*)d_ws;
    float* wT      = ws;                // 131072
    float* en_inv  = wT + 131072;       // 8192
    float* en_norm = en_inv + 8192;     // 8192
    float* inv_zn  = en_norm + 8192;    // 16384
    int*   tok_i   = (int*)(inv_zn + 16384); // 16384

    k_wT<<<512, 256, 0, stream>>>(w_pre, wT);
    k_en<<<2048, 256, 0, stream>>>(emb, en_inv, en_norm);
    dim3 g1(Mm / 64, Ee / 64);
    k_gemm1<<<g1, 256, 0, stream>>>(x, wT, b_pre, z);
    k_znorm<<<Mm / 256, 256, 0, stream>>>(z, inv_zn);
    k_Asplit<<<2048, 256, 0, stream>>>(z, inv_zn, Ahi, Alo);
    k_Bsplit<<<4096, 256, 0, stream>>>(emb, en_inv, Bhi, Blo);
    k_sims<<<2048, 512, 0, stream>>>(Ahi, Alo, Bhi, Blo, part_v, part_i);
    k_reduce<<<Mm / 8, 256, 0, stream>>>(part_v, part_i, tok_i, tokf);
    k_final<<<(int)(8388608 / 256), 256, 0, stream>>>(z, emb, tok_i, inv_zn, en_inv, en_norm, zq, dec);
}

// Round 5
// 426.363 us; speedup vs baseline: 1.6309x; 1.6309x over previous
//
#include <hip/hip_runtime.h>
#include <math.h>

#define EPSF 1e-8f
#define MARGIN 4e-3f

constexpr int Bn = 16, Cc = 256, HW = 1024, Ee = 512, Vv = 8192;
constexpr int Mm = Bn * HW; // 16384 pixels

// d_out float offsets: z | z_q | decoder_input | tokens(float)
constexpr long O_Z   = 0;
constexpr long O_ZQ  = 8388608;
constexpr long O_DEC = 16777216;
constexpr long O_TOK = 25165824;

typedef __attribute__((ext_vector_type(8))) short s16x8;
typedef __attribute__((ext_vector_type(4))) short s16x4;
typedef __attribute__((ext_vector_type(8))) _Float16 f16x8;
typedef __attribute__((ext_vector_type(4))) float f32x4;

__device__ __forceinline__ unsigned short f2h(float x) {
    _Float16 h = (_Float16)x;
    return __builtin_bit_cast(unsigned short, h);
}
__device__ __forceinline__ float h2f(unsigned short b) {
    return (float)__builtin_bit_cast(_Float16, b);
}

// ---------------- small prep kernels ----------------

__global__ void k_wT(const float* __restrict__ w, float* __restrict__ wT) {
    int gid = blockIdx.x * 256 + threadIdx.x;      // 0..131071
    int c = gid >> 9, e = gid & 511;
    wT[gid] = w[e * Cc + c];                        // wT[c][e]
}

__global__ void k_en(const float* __restrict__ emb, float* __restrict__ en_inv,
                     float* __restrict__ en_norm) {
    int v = blockIdx.x * 4 + (threadIdx.x >> 6);    // one wave per row
    int lane = threadIdx.x & 63;
    const float* row = emb + (long)v * Ee;
    float s = 0.f;
#pragma unroll
    for (int j = 0; j < 8; ++j) { float xv = row[lane + 64 * j]; s += xv * xv; }
#pragma unroll
    for (int off = 32; off; off >>= 1) s += __shfl_xor(s, off);
    if (lane == 0) {
        float n = sqrtf(s);
        en_norm[v] = EPSF + n;
        en_inv[v]  = 1.0f / (EPSF + n);
    }
}

// ---------------- GEMM1: z[b][e][hw] = sum_c x[b][c][hw]*w[e][c] + b[e] ----------------

__global__ __launch_bounds__(256) void k_gemm1(const float* __restrict__ x,
                                               const float* __restrict__ wT,
                                               const float* __restrict__ bias,
                                               float* __restrict__ z) {
    __shared__ float As[32][64];
    __shared__ float Bs[32][64];
    int m0 = blockIdx.x * 64;                 // pixel tile
    int b = m0 >> 10, hw0 = m0 & 1023;
    int e0 = blockIdx.y * 64;
    int t = threadIdx.x;
    int mi = t >> 4, ni = t & 15;
    float acc[4][4] = {};
    for (int c0 = 0; c0 < Cc; c0 += 32) {
#pragma unroll
        for (int q = 0; q < 2; ++q) {
            int f = t + 256 * q;
            int kk = f >> 4, m4 = (f & 15) * 4;
            *(float4*)&As[kk][m4] = *(const float4*)(x + ((long)(b * Cc + c0 + kk)) * HW + hw0 + m4);
            *(float4*)&Bs[kk][m4] = *(const float4*)(wT + (long)(c0 + kk) * Ee + e0 + m4);
        }
        __syncthreads();
#pragma unroll
        for (int kk = 0; kk < 32; ++kk) {
            float4 a = *(float4*)&As[kk][mi * 4];
            float4 bv = *(float4*)&Bs[kk][ni * 4];
            float av[4] = {a.x, a.y, a.z, a.w};
            float bb[4] = {bv.x, bv.y, bv.z, bv.w};
#pragma unroll
            for (int r = 0; r < 4; ++r)
#pragma unroll
                for (int c = 0; c < 4; ++c) acc[r][c] = fmaf(av[r], bb[c], acc[r][c]);
        }
        __syncthreads();
    }
#pragma unroll
    for (int c = 0; c < 4; ++c) {
        int e = e0 + ni * 4 + c;
        float be = bias[e];
        float4 o = make_float4(acc[0][c] + be, acc[1][c] + be, acc[2][c] + be, acc[3][c] + be);
        *(float4*)(z + ((long)(b * Ee + e)) * HW + hw0 + mi * 4) = o;
    }
}

// per-pixel 1/(EPS+||z||), 4 e-chunks in parallel
__global__ void k_znorm(const float* __restrict__ z, float* __restrict__ inv_zn) {
    __shared__ float partial[4][64];
    int lp = threadIdx.x & 63;
    int q = threadIdx.x >> 6;
    int p = blockIdx.x * 64 + lp;
    int b = p >> 10, hw = p & 1023;
    const float* base = z + ((long)(b * Ee + q * 128)) * HW + hw;
    float s = 0.f;
    for (int e = 0; e < 128; ++e) { float xv = base[(long)e * HW]; s = fmaf(xv, xv, s); }
    partial[q][lp] = s;
    __syncthreads();
    if (threadIdx.x < 64) {
        float t = ((partial[0][threadIdx.x] + partial[1][threadIdx.x]) +
                   partial[2][threadIdx.x]) + partial[3][threadIdx.x];
        inv_zn[blockIdx.x * 64 + threadIdx.x] = 1.0f / (EPSF + sqrtf(t));
    }
}

// ---------------- A split: zn -> A_hi/A_lo fp16 [16384][512] (pixel-major) ----------------

__global__ void k_Asplit(const float* __restrict__ z, const float* __restrict__ inv_zn,
                         unsigned short* __restrict__ Ahi, unsigned short* __restrict__ Alo) {
    __shared__ float tile[64][65];
    int p0 = (blockIdx.x >> 3) * 64;   // 256 p-tiles
    int e0 = (blockIdx.x & 7) * 64;    // 8 e-tiles
    int b = p0 >> 10, hw0 = p0 & 1023;
    int t = threadIdx.x;
#pragma unroll
    for (int q = 0; q < 4; ++q) {
        int f = t + 256 * q;
        int e_l = f >> 4, p4 = (f & 15) * 4;
        float4 d = *(const float4*)(z + ((long)(b * Ee + e0 + e_l)) * HW + hw0 + p4);
        tile[e_l][p4 + 0] = d.x; tile[e_l][p4 + 1] = d.y;
        tile[e_l][p4 + 2] = d.z; tile[e_l][p4 + 3] = d.w;
    }
    __syncthreads();
#pragma unroll
    for (int q = 0; q < 4; ++q) {
        int f = t + 256 * q;
        int p_l = f >> 4, e4 = (f & 15) * 4;
        float inv = inv_zn[p0 + p_l];
        s16x4 h, lo;
#pragma unroll
        for (int j = 0; j < 4; ++j) {
            float xv = tile[e4 + j][p_l] * inv;
            unsigned short hh = f2h(xv);
            h[j]  = (short)hh;
            lo[j] = (short)f2h(xv - h2f(hh));
        }
        long off = (long)(p0 + p_l) * Ee + e0 + e4;
        *(s16x4*)(Ahi + off) = h;
        *(s16x4*)(Alo + off) = lo;
    }
}

// ---------------- B: emb*en_inv -> fp16 [8192][512] ----------------

__global__ void k_Bh(const float* __restrict__ emb, const float* __restrict__ en_inv,
                     unsigned short* __restrict__ Bhi) {
    int gid = blockIdx.x * 256 + threadIdx.x;   // 0..1048575
    int v = gid >> 7, c4 = (gid & 127) * 4;
    float inv = en_inv[v];
    float4 d = *(const float4*)(emb + (long)v * Ee + c4);
    s16x4 h;
    h[0] = (short)f2h(d.x * inv); h[1] = (short)f2h(d.y * inv);
    h[2] = (short)f2h(d.z * inv); h[3] = (short)f2h(d.w * inv);
    *(s16x4*)(Bhi + (long)v * Ee + c4) = h;
}

// ---------------- single-pass fp16 MFMA sims GEMM + winner/extras epilogue ----------------
// 8192 blocks (128 m-tiles x 64 v-tiles), 256 thr = 4 waves (2x2). K=512 (8 tiles).
// Same proven R3 structure. Epilogue: per-pixel stripe winner -> part[ p ][ by ],
// plus every col with S16 >= stripe_max - MARGIN appended to extras[p][<64].

__global__ __launch_bounds__(256, 2) void k_sims(const unsigned short* __restrict__ Ahi,
                                                 const unsigned short* __restrict__ Bhi,
                                                 float* __restrict__ part_v,
                                                 int* __restrict__ part_i,
                                                 float2* __restrict__ extras,
                                                 int* __restrict__ cnt) {
    __shared__ short As[128 * 64];
    __shared__ short Bs[128 * 64];
    __shared__ float red_v[2][2][64];
    __shared__ int   red_i[2][2][64];
    __shared__ float red_m[2][64];
    __shared__ int   red_wi[2][64];

    int t = threadIdx.x;
    int wg = blockIdx.x;
    int xcd = wg & 7, r = wg >> 3;
    int bx = xcd * 16 + (r & 15);     // 0..127  (m-tile), XCD-chunked
    int by = r >> 4;                  // 0..63   (v-tile)
    long m0 = (long)bx * 128, n0 = (long)by * 128;

    int wid = t >> 6, l = t & 63;
    int wr = wid >> 1, wc = wid & 1;
    int srow = t >> 3, sslot = t & 7;
    int l15 = l & 15, lg = l >> 4;

    f32x4 acc[4][4];
#pragma unroll
    for (int i = 0; i < 4; ++i)
#pragma unroll
        for (int j = 0; j < 4; ++j) acc[i][j] = (f32x4){0.f, 0.f, 0.f, 0.f};

    for (int kt = 0; kt < 8; ++kt) {
        int k0 = kt * 64;
        s16x8 ra[4], rb[4];
#pragma unroll
        for (int q = 0; q < 4; ++q) {
            int rr = srow + 32 * q;
            ra[q] = *(const s16x8*)(Ahi + (m0 + rr) * Ee + k0 + sslot * 8);
            rb[q] = *(const s16x8*)(Bhi + (n0 + rr) * Ee + k0 + sslot * 8);
        }
        __syncthreads();   // previous compute done reading LDS
#pragma unroll
        for (int q = 0; q < 4; ++q) {
            int rr = srow + 32 * q;
            int sw = (sslot ^ (rr & 7)) * 8;
            *(s16x8*)&As[rr * 64 + sw] = ra[q];
            *(s16x8*)&Bs[rr * 64 + sw] = rb[q];
        }
        __syncthreads();   // tiles visible
        s16x8 af[4][2], bf[4][2];
#pragma unroll
        for (int mt = 0; mt < 4; ++mt)
#pragma unroll
            for (int kk = 0; kk < 2; ++kk) {
                int row = wr * 64 + mt * 16 + l15;
                int g = kk * 4 + lg;
                af[mt][kk] = *(s16x8*)&As[row * 64 + ((g ^ (row & 7)) * 8)];
                int nrow = wc * 64 + mt * 16 + l15;
                bf[mt][kk] = *(s16x8*)&Bs[nrow * 64 + ((g ^ (nrow & 7)) * 8)];
            }
#pragma unroll
        for (int kk = 0; kk < 2; ++kk)
#pragma unroll
            for (int mt = 0; mt < 4; ++mt)
#pragma unroll
                for (int nt = 0; nt < 4; ++nt)
                    acc[mt][nt] = __builtin_amdgcn_mfma_f32_16x16x32_f16(
                        __builtin_bit_cast(f16x8, af[mt][kk]),
                        __builtin_bit_cast(f16x8, bf[nt][kk]), acc[mt][nt], 0, 0, 0);
    }

    // ---- winner epilogue (C/D: col = l&15, row = (l>>4)*4 + reg) ----
#pragma unroll
    for (int mt = 0; mt < 4; ++mt)
#pragma unroll
        for (int rg = 0; rg < 4; ++rg) {
            float best = -3e38f; int bi = 0x7FFFFFFF;
#pragma unroll
            for (int nt = 0; nt < 4; ++nt) {
                float val = acc[mt][nt][rg];
                int idx = (int)n0 + wc * 64 + nt * 16 + l15;
                if (val > best) { best = val; bi = idx; }
            }
#pragma unroll
            for (int off = 1; off < 16; off <<= 1) {
                float ov = __shfl_xor(best, off);
                int oi = __shfl_xor(bi, off);
                if (ov > best || (ov == best && oi < bi)) { best = ov; bi = oi; }
            }
            if (l15 == 0) {
                int rloc = mt * 16 + lg * 4 + rg;
                red_v[wr][wc][rloc] = best;
                red_i[wr][wc][rloc] = bi;
            }
        }
    __syncthreads();
    if (t < 128) {
        int wr_ = t >> 6, rloc = t & 63;
        float va = red_v[wr_][0][rloc]; int ia = red_i[wr_][0][rloc];
        float vb = red_v[wr_][1][rloc]; int ib = red_i[wr_][1][rloc];
        if (vb > va || (vb == va && ib < ia)) { va = vb; ia = ib; }
        long m = m0 + wr_ * 64 + rloc;
        part_v[m * 64 + by] = va;
        part_i[m * 64 + by] = ia;
        red_m[wr_][rloc] = va;
        red_wi[wr_][rloc] = ia;
    }
    __syncthreads();
    // ---- extras: every non-winner col within MARGIN of the stripe max ----
#pragma unroll
    for (int mt = 0; mt < 4; ++mt)
#pragma unroll
        for (int rg = 0; rg < 4; ++rg) {
            int rloc = mt * 16 + lg * 4 + rg;
            float bm = red_m[wr][rloc];
            int wi_ = red_wi[wr][rloc];
            long p = m0 + wr * 64 + rloc;
            float thr = bm - MARGIN;
#pragma unroll
            for (int nt = 0; nt < 4; ++nt) {
                float val = acc[mt][nt][rg];
                int idx = (int)n0 + wc * 64 + nt * 16 + l15;
                if (val >= thr && idx != wi_) {
                    int slot = atomicAdd(&cnt[p], 1);
                    if (slot < 64) extras[p * 64 + slot] = make_float2(val, __int_as_float(idx));
                }
            }
        }
}

// ---------------- k_pick: per-pixel global m1, candidate set, exact f32 rescore ----------------

__global__ __launch_bounds__(256) void k_pick(const float* __restrict__ part_v,
                                              const int* __restrict__ part_i,
                                              const float2* __restrict__ extras,
                                              const int* __restrict__ cnt,
                                              const unsigned short* __restrict__ Ahi,
                                              const unsigned short* __restrict__ Alo,
                                              const float* __restrict__ emb,
                                              const float* __restrict__ en_inv,
                                              int* __restrict__ tok_i,
                                              float* __restrict__ tok_f) {
    int p = blockIdx.x * 4 + (threadIdx.x >> 6);
    int lane = threadIdx.x & 63;
    float wv = part_v[(long)p * 64 + lane];
    int wi = part_i[(long)p * 64 + lane];
    // global fp16 max over the 64 stripe winners
    float m1 = wv;
#pragma unroll
    for (int off = 1; off < 64; off <<= 1) {
        float ov = __shfl_xor(m1, off);
        if (ov > m1) m1 = ov;
    }
    float thr = m1 - MARGIN;
    int n = cnt[p]; if (n > 64) n = 64;
    float ev = -3e38f; int ei = 0;
    if (lane < n) {
        float2 e2 = extras[(long)p * 64 + lane];
        ev = e2.x; ei = __float_as_int(e2.y);
    }
    unsigned long long mw = __ballot(wv >= thr);
    unsigned long long me = __ballot(ev >= thr);
    // preload this pixel's zn row slice (reconstructed f32)
    s16x8 ah = *(const s16x8*)(Ahi + (long)p * Ee + lane * 8);
    s16x8 al = *(const s16x8*)(Alo + (long)p * Ee + lane * 8);
    float a[8];
#pragma unroll
    for (int j = 0; j < 8; ++j)
        a[j] = h2f((unsigned short)ah[j]) + h2f((unsigned short)al[j]);

    float best = -3e38f; int bi = 0x7FFFFFFF;
    auto rescore = [&](int v) {
        const float* er = emb + (long)v * Ee + lane * 8;
        float4 b0 = *(const float4*)er;
        float4 b1 = *(const float4*)(er + 4);
        float s = 0.f;
        s = fmaf(a[0], b0.x, s); s = fmaf(a[1], b0.y, s);
        s = fmaf(a[2], b0.z, s); s = fmaf(a[3], b0.w, s);
        s = fmaf(a[4], b1.x, s); s = fmaf(a[5], b1.y, s);
        s = fmaf(a[6], b1.z, s); s = fmaf(a[7], b1.w, s);
#pragma unroll
        for (int off = 1; off < 64; off <<= 1) s += __shfl_xor(s, off);
        s *= en_inv[v];
        if (s > best || (s == best && v < bi)) { best = s; bi = v; }
    };
    while (mw) {
        int b = __ffsll(mw) - 1; mw &= mw - 1;
        rescore(__shfl(wi, b));
    }
    while (me) {
        int b = __ffsll(me) - 1; me &= me - 1;
        rescore(__shfl(ei, b));
    }
    if (lane == 0) { tok_i[p] = bi; tok_f[p] = (float)bi; }
}

// ---------------- finalize: z_q gather + straight-through blend ----------------

__global__ void k_final(const float* __restrict__ z, const float* __restrict__ emb,
                        const int* __restrict__ tok, const float* __restrict__ inv_zn,
                        const float* __restrict__ en_inv, const float* __restrict__ en_norm,
                        float* __restrict__ zq, float* __restrict__ dec) {
    long gid = (long)blockIdx.x * 256 + threadIdx.x;   // 0..8388607
    int hw = (int)(gid & 1023);
    int b  = (int)(gid >> 19);
    int p  = (b << 10) | hw;
    int e  = (int)((gid >> 10) & 511);
    int tk = tok[p];
    float zqv = emb[(long)tk * Ee + e];
    float nq  = en_norm[tk];
    float nzq = zqv * en_inv[tk];
    float zv  = z[gid];
    float nz  = zv * inv_zn[p];
    zq[gid]  = zqv;
    dec[gid] = (nz + (nzq - nz)) * nq;
}

// ---------------- launch ----------------

extern "C" void kernel_launch(void* const* d_in, const int* in_sizes, int n_in,
                              void* d_out, int out_size, void* d_ws, size_t ws_size,
                              hipStream_t stream) {
    const float* x     = (const float*)d_in[0];
    const float* w_pre = (const float*)d_in[1];
    const float* b_pre = (const float*)d_in[2];
    const float* emb   = (const float*)d_in[3];

    float* out  = (float*)d_out;
    float* z    = out + O_Z;
    float* zq   = out + O_ZQ;
    float* dec  = out + O_DEC;
    float* tokf = out + O_TOK;

    // zq region (32MB): Ahi | Alo  fp16 [16384][512] each (dead until k_final)
    unsigned short* Ahi = (unsigned short*)zq;
    unsigned short* Alo = Ahi + (long)Mm * Ee;
    // dec region (32MB floats, 8M): Bhi(2M) | part_v(1M) | part_i(1M) | extras(2M) | cnt
    unsigned short* Bhi = (unsigned short*)dec;
    float*  part_v = dec + 2 * 1024 * 1024;
    int*    part_i = (int*)(dec + 3 * 1024 * 1024);
    float2* extras = (float2*)(dec + 4 * 1024 * 1024);
    int*    cnt    = (int*)(dec + 6 * 1024 * 1024);

    float* ws      = (float*)d_ws;      // ~704 KB of d_ws used (as in passing R1-R3)
    float* wT      = ws;                // 131072
    float* en_inv  = wT + 131072;       // 8192
    float* en_norm = en_inv + 8192;     // 8192
    float* inv_zn  = en_norm + 8192;    // 16384
    int*   tok_i   = (int*)(inv_zn + 16384); // 16384

    k_wT<<<512, 256, 0, stream>>>(w_pre, wT);
    k_en<<<2048, 256, 0, stream>>>(emb, en_inv, en_norm);
    dim3 g1(Mm / 64, Ee / 64);
    k_gemm1<<<g1, 256, 0, stream>>>(x, wT, b_pre, z);
    k_znorm<<<Mm / 64, 256, 0, stream>>>(z, inv_zn);
    k_Asplit<<<2048, 256, 0, stream>>>(z, inv_zn, Ahi, Alo);
    k_Bh<<<4096, 256, 0, stream>>>(emb, en_inv, Bhi);
    hipMemsetAsync((void*)cnt, 0, Mm * sizeof(int), stream);
    k_sims<<<8192, 256, 0, stream>>>(Ahi, Bhi, part_v, part_i, extras, cnt);
    k_pick<<<Mm / 4, 256, 0, stream>>>(part_v, part_i, extras, cnt, Ahi, Alo, emb,
                                       en_inv, tok_i, tokf);
    k_final<<<(int)(8388608 / 256), 256, 0, stream>>>(z, emb, tok_i, inv_zn, en_inv, en_norm, zq, dec);
}